// Round 3
// baseline (349.543 us; speedup 1.0000x reference)
//
#include <hip/hip_runtime.h>

// Problem constants (fixed by the reference file).
static constexpr int B = 16;
static constexpr int N = 250000;   // 15625 * 16
static constexpr int F = 500000;
static constexpr int E = 6 * F;    // directed edges = 3,000,000 (even per vertex)
static constexpr int RW = 48;      // ushorts per vt row: 3 comps * 16 batches (96 B)

// ---- workspace layout (bytes) ----
//   vt    : ushort[N][48]  24,000,000  bf16 positions, layout (N, comp, batch)
//   adj   : int[E]         12,000,000  CSR adjacency values
//   deg   : uint[N]         1,000,000
//   cnt   : uint (padded to 256)
//   start : uint[N]         1,000,000  (begin at alloc; advanced to end by fill)
static constexpr size_t OFF_VT  = 0;
static constexpr size_t OFF_ADJ = (size_t)N * RW * 2;                  // 24,000,000
static constexpr size_t OFF_DEG = OFF_ADJ + (size_t)E * sizeof(int);   // 36,000,000
static constexpr size_t OFF_CNT = OFF_DEG + (size_t)N * sizeof(unsigned); // 37,000,000
static constexpr size_t OFF_STA = OFF_CNT + 256;                       // 37,000,256
static constexpr size_t WS_NEED = OFF_STA + (size_t)N * sizeof(unsigned); // ~38 MB (< proven 63 MB)

__device__ __forceinline__ unsigned short f2bf(float f) {
    unsigned u = __float_as_uint(f);
    return (unsigned short)((u + 0x7FFFu + ((u >> 16) & 1u)) >> 16);  // RNE
}
__device__ __forceinline__ float bf2f(unsigned short u) {
    return __uint_as_float((unsigned)u << 16);
}

// Fused: (B,N,3) fp32 -> (N,3,16) bf16 transpose  +  degree count.
__global__ __launch_bounds__(256) void uls_setup(
    const float* __restrict__ vert, const int* __restrict__ faces,
    unsigned short* __restrict__ vt, unsigned* __restrict__ deg)
{
    __shared__ unsigned short lus[16 * RW];   // 768 ushorts
    int t = threadIdx.x;
    int n0 = blockIdx.x * 16;
    int b = t >> 4, v = t & 15;
    const float* s = vert + (size_t)b * (N * 3) + (size_t)(n0 + v) * 3;  // coalesced 192 B / 16 lanes
    lus[v * RW + 0 * 16 + b] = f2bf(s[0]);
    lus[v * RW + 1 * 16 + b] = f2bf(s[1]);
    lus[v * RW + 2 * 16 + b] = f2bf(s[2]);
    __syncthreads();
    // 768 ushorts = 192 uint2, threads 0..191 write 8 B each (coalesced 1536 B)
    const uint2* lu2 = (const uint2*)lus;
    uint2* d2 = (uint2*)(vt + (size_t)n0 * RW);
    if (t < 192) d2[t] = lu2[t];
    // count part: 4M threads cover F=500k faces
    int f = blockIdx.x * 256 + t;
    if (f < F) {
        int a = faces[3 * f + 0], bb = faces[3 * f + 1], c = faces[3 * f + 2];
        atomicAdd(&deg[a], 2u);
        atomicAdd(&deg[bb], 2u);
        atomicAdd(&deg[c], 2u);
    }
}

// start[n] = block-local exclusive scan + atomically allocated block base.
__global__ __launch_bounds__(256) void uls_alloc(
    const unsigned* __restrict__ deg, unsigned* __restrict__ start,
    unsigned* __restrict__ counter)
{
    __shared__ unsigned s[256];
    __shared__ unsigned base;
    int t = threadIdx.x;
    int n = blockIdx.x * 256 + t;
    unsigned d = (n < N) ? deg[n] : 0u;
    s[t] = d;
    __syncthreads();
    for (int off = 1; off < 256; off <<= 1) {
        unsigned v = (t >= off) ? s[t - off] : 0u;
        __syncthreads();
        s[t] += v;
        __syncthreads();
    }
    if (t == 255) base = atomicAdd(counter, s[255]);
    __syncthreads();
    if (n < N) start[n] = base + (s[t] - d);
}

// Allocation cursor IS start[]: atomicAdd returns the absolute slot.
// After this kernel start[n] == begin + deg[n] (the region end).
__global__ __launch_bounds__(256) void uls_fill(
    const int* __restrict__ faces, unsigned* __restrict__ start,
    int* __restrict__ adj)
{
    int f = blockIdx.x * 256 + threadIdx.x;
    if (f >= F) return;
    int a = faces[3 * f + 0], b = faces[3 * f + 1], c = faces[3 * f + 2];
    unsigned p;
    p = atomicAdd(&start[a], 2u); *(int2*)(adj + p) = make_int2(b, c);  // p even -> 8 B aligned
    p = atomicAdd(&start[b], 2u); *(int2*)(adj + p) = make_int2(a, c);
    p = atomicAdd(&start[c], 2u); *(int2*)(adj + p) = make_int2(a, b);
}

// 16 lanes share a vertex, span batches 0..15; each neighbor row read is
// three fully-used 32 B segments (96 B/row bf16). No atomics.
__global__ __launch_bounds__(256) void uls_gather(
    const unsigned short* __restrict__ vt, const int* __restrict__ adj,
    const unsigned* __restrict__ send,   // region END per vertex (post-fill start[])
    const unsigned* __restrict__ deg,
    float* __restrict__ out)
{
    __shared__ float lds[16 * 17];
    int t = threadIdx.x;
    int b = t & 15, v = t >> 4;
    int n = blockIdx.x * 16 + v;

    unsigned d  = deg[n];           // uniform per 16-lane group
    unsigned s0 = send[n] - d;      // region begin

    float ax = 0.f, ay = 0.f, az = 0.f;
    unsigned j = 0;
    for (; j + 4 <= d; j += 4) {    // 4 independent row streams in flight
        int2 p0 = *(const int2*)(adj + s0 + j);
        int2 p1 = *(const int2*)(adj + s0 + j + 2);
        const unsigned short* r0 = vt + (size_t)p0.x * RW;
        const unsigned short* r1 = vt + (size_t)p0.y * RW;
        const unsigned short* r2 = vt + (size_t)p1.x * RW;
        const unsigned short* r3 = vt + (size_t)p1.y * RW;
        ax += (bf2f(r0[b])      + bf2f(r1[b]))      + (bf2f(r2[b])      + bf2f(r3[b]));
        ay += (bf2f(r0[16 + b]) + bf2f(r1[16 + b])) + (bf2f(r2[16 + b]) + bf2f(r3[16 + b]));
        az += (bf2f(r0[32 + b]) + bf2f(r1[32 + b])) + (bf2f(r2[32 + b]) + bf2f(r3[32 + b]));
    }
    if (j < d) {                    // deg is even: remainder is exactly 0 or 2
        int2 p0 = *(const int2*)(adj + s0 + j);
        const unsigned short* r0 = vt + (size_t)p0.x * RW;
        const unsigned short* r1 = vt + (size_t)p0.y * RW;
        ax += bf2f(r0[b])      + bf2f(r1[b]);
        ay += bf2f(r0[16 + b]) + bf2f(r1[16 + b]);
        az += bf2f(r0[32 + b]) + bf2f(r1[32 + b]);
    }

    const unsigned short* rs = vt + (size_t)n * RW;
    float inv = 1.0f / fmaxf((float)d, 1.0f);
    float lx = ax * inv - bf2f(rs[b]);
    float ly = ay * inv - bf2f(rs[16 + b]);
    float lz = az * inv - bf2f(rs[32 + b]);
    lds[v * 17 + b] = sqrtf(lx * lx + ly * ly + lz * lz);
    __syncthreads();
    int vo = t & 15, bo = t >> 4;
    out[(size_t)bo * N + blockIdx.x * 16 + vo] = lds[vo * 17 + bo];  // coalesced
}

extern "C" void kernel_launch(void* const* d_in, const int* in_sizes, int n_in,
                              void* d_out, int out_size, void* d_ws, size_t ws_size,
                              hipStream_t stream) {
    const float* vert  = (const float*)d_in[0];   // (B, N, 3) fp32
    const int*   faces = (const int*)d_in[1];     // (F, 3) int32
    float* out = (float*)d_out;                   // (B, N) fp32
    char* ws = (char*)d_ws;
    (void)ws_size;  // WS_NEED ~38 MB; harness proven >= 63 MB in round 2

    unsigned short* vt      = (unsigned short*)(ws + OFF_VT);
    int*            adj     = (int*)(ws + OFF_ADJ);
    unsigned*       deg     = (unsigned*)(ws + OFF_DEG);
    unsigned*       counter = (unsigned*)(ws + OFF_CNT);
    unsigned*       start   = (unsigned*)(ws + OFF_STA);

    // zero deg + counter in one contiguous memset (start is fully written by alloc)
    hipMemsetAsync(ws + OFF_DEG, 0, (OFF_CNT + 256) - OFF_DEG, stream);

    uls_setup<<<N / 16, 256, 0, stream>>>(vert, faces, vt, deg);
    uls_alloc<<<(N + 255) / 256, 256, 0, stream>>>(deg, start, counter);
    uls_fill<<<(F + 255) / 256, 256, 0, stream>>>(faces, start, adj);
    uls_gather<<<N / 16, 256, 0, stream>>>(vt, adj, start, deg, out);
}

// Round 4
// 267.073 us; speedup vs baseline: 1.3088x; 1.3088x over previous
//
#include <hip/hip_runtime.h>

// Problem constants (fixed by the reference file).
static constexpr int B = 16;
static constexpr int N = 250000;   // 15625 * 16
static constexpr int F = 500000;
static constexpr int C3 = 3 * F;   // corners = 1,500,000
static constexpr int E = 6 * F;    // directed edges = 3,000,000 (even per vertex)
static constexpr int RW = 48;      // ushorts per vt row: 3 comps * 16 batches (96 B)

// ---- workspace layout (bytes) ----
//   vt    : ushort[N][48]  24,000,000  bf16 positions, layout (N, comp, batch)
//   adj   : int[E]         12,000,000  CSR adjacency values
//   deg   : uint[N]         1,000,000
//   cnt   : uint (padded to 256)
//   start : uint[N]         1,000,000  region begin (exclusive scan of deg)
//   rank  : uint[3F]        6,000,000  per-corner offset within its region
static constexpr size_t OFF_VT  = 0;
static constexpr size_t OFF_ADJ = (size_t)N * RW * 2;                      // 24,000,000
static constexpr size_t OFF_DEG = OFF_ADJ + (size_t)E * sizeof(int);       // 36,000,000
static constexpr size_t OFF_CNT = OFF_DEG + (size_t)N * sizeof(unsigned);  // 37,000,000
static constexpr size_t OFF_STA = OFF_CNT + 256;                           // 37,000,256
static constexpr size_t OFF_RNK = OFF_STA + (size_t)N * sizeof(unsigned);  // 38,000,256
static constexpr size_t WS_NEED = OFF_RNK + (size_t)C3 * sizeof(unsigned); // ~44 MB (< proven 63 MB)

__device__ __forceinline__ unsigned short f2bf(float f) {
    unsigned u = __float_as_uint(f);
    return (unsigned short)((u + 0x7FFFu + ((u >> 16) & 1u)) >> 16);  // RNE
}
__device__ __forceinline__ float bf2f(unsigned short u) {
    return __uint_as_float((unsigned)u << 16);
}

// (B,N,3) fp32 -> (N,3,16) bf16 transpose. 16 vertices/block, coalesced both sides.
__global__ __launch_bounds__(256) void uls_transpose(
    const float* __restrict__ vert, unsigned short* __restrict__ vt)
{
    __shared__ unsigned short lus[16 * RW];   // 768 ushorts
    int t = threadIdx.x;
    int n0 = blockIdx.x * 16;
    int b = t >> 4, v = t & 15;
    const float* s = vert + (size_t)b * (N * 3) + (size_t)(n0 + v) * 3;
    lus[v * RW + 0 * 16 + b] = f2bf(s[0]);
    lus[v * RW + 1 * 16 + b] = f2bf(s[1]);
    lus[v * RW + 2 * 16 + b] = f2bf(s[2]);
    __syncthreads();
    // 768 ushorts = 192 uint2; threads 0..191 write 8 B each (coalesced 1536 B)
    const uint2* lu2 = (const uint2*)lus;
    uint2* d2 = (uint2*)(vt + (size_t)n0 * RW);
    if (t < 192) d2[t] = lu2[t];
}

// One corner per thread: rank[e] = previous count at that vertex (even), deg += 2.
// Single wave-wide atomic per thread, max occupancy -> max outstanding requests.
__global__ __launch_bounds__(256) void uls_rank(
    const int* __restrict__ faces, unsigned* __restrict__ deg,
    unsigned* __restrict__ rank)
{
    int e = blockIdx.x * 256 + threadIdx.x;
    if (e >= C3) return;
    int dst = faces[e];                      // coalesced 4 B
    rank[e] = atomicAdd(&deg[dst], 2u);      // the only atomic in the pipeline
}

// start[n] = block-local exclusive scan + atomically allocated block base.
__global__ __launch_bounds__(256) void uls_alloc(
    const unsigned* __restrict__ deg, unsigned* __restrict__ start,
    unsigned* __restrict__ counter)
{
    __shared__ unsigned s[256];
    __shared__ unsigned base;
    int t = threadIdx.x;
    int n = blockIdx.x * 256 + t;
    unsigned d = (n < N) ? deg[n] : 0u;
    s[t] = d;
    __syncthreads();
    for (int off = 1; off < 256; off <<= 1) {
        unsigned v = (t >= off) ? s[t - off] : 0u;
        __syncthreads();
        s[t] += v;
        __syncthreads();
    }
    if (t == 255) base = atomicAdd(counter, s[255]);
    __syncthreads();
    if (n < N) start[n] = base + (s[t] - d);
}

// Atomic-free placement: slot = start[dst] + rank[e].
// start[] is 1 MB, L2-resident read-only; the int2 store is the only scatter.
__global__ __launch_bounds__(256) void uls_fill(
    const int* __restrict__ faces, const unsigned* __restrict__ start,
    const unsigned* __restrict__ rank, int* __restrict__ adj)
{
    int e = blockIdx.x * 256 + threadIdx.x;
    if (e >= C3) return;
    int f = e / 3;
    int c = e - 3 * f;
    int a  = faces[3 * f + 0];
    int b  = faces[3 * f + 1];
    int cc = faces[3 * f + 2];
    int dst = (c == 0) ? a : (c == 1) ? b : cc;
    int p0  = (c == 0) ? b : a;
    int p1  = (c == 2) ? b : cc;
    unsigned p = start[dst] + rank[e];       // both even -> 8 B aligned
    *(int2*)(adj + p) = make_int2(p0, p1);
}

// 16 lanes share a vertex, span batches 0..15; each neighbor row read is
// three fully-used 32 B segments (96 B/row bf16). No atomics.
__global__ __launch_bounds__(256) void uls_gather(
    const unsigned short* __restrict__ vt, const int* __restrict__ adj,
    const unsigned* __restrict__ start, const unsigned* __restrict__ deg,
    float* __restrict__ out)
{
    __shared__ float lds[16 * 17];
    int t = threadIdx.x;
    int b = t & 15, v = t >> 4;
    int n = blockIdx.x * 16 + v;

    unsigned d  = deg[n];           // uniform per 16-lane group
    unsigned s0 = start[n];         // region begin (fill does not advance it)

    float ax = 0.f, ay = 0.f, az = 0.f;
    unsigned j = 0;
    for (; j + 4 <= d; j += 4) {    // 4 independent row streams in flight
        int2 p0 = *(const int2*)(adj + s0 + j);
        int2 p1 = *(const int2*)(adj + s0 + j + 2);
        const unsigned short* r0 = vt + (size_t)p0.x * RW;
        const unsigned short* r1 = vt + (size_t)p0.y * RW;
        const unsigned short* r2 = vt + (size_t)p1.x * RW;
        const unsigned short* r3 = vt + (size_t)p1.y * RW;
        ax += (bf2f(r0[b])      + bf2f(r1[b]))      + (bf2f(r2[b])      + bf2f(r3[b]));
        ay += (bf2f(r0[16 + b]) + bf2f(r1[16 + b])) + (bf2f(r2[16 + b]) + bf2f(r3[16 + b]));
        az += (bf2f(r0[32 + b]) + bf2f(r1[32 + b])) + (bf2f(r2[32 + b]) + bf2f(r3[32 + b]));
    }
    if (j < d) {                    // deg even: remainder is exactly 0 or 2
        int2 p0 = *(const int2*)(adj + s0 + j);
        const unsigned short* r0 = vt + (size_t)p0.x * RW;
        const unsigned short* r1 = vt + (size_t)p0.y * RW;
        ax += bf2f(r0[b])      + bf2f(r1[b]);
        ay += bf2f(r0[16 + b]) + bf2f(r1[16 + b]);
        az += bf2f(r0[32 + b]) + bf2f(r1[32 + b]);
    }

    const unsigned short* rs = vt + (size_t)n * RW;
    float inv = 1.0f / fmaxf((float)d, 1.0f);
    float lx = ax * inv - bf2f(rs[b]);
    float ly = ay * inv - bf2f(rs[16 + b]);
    float lz = az * inv - bf2f(rs[32 + b]);
    lds[v * 17 + b] = sqrtf(lx * lx + ly * ly + lz * lz);
    __syncthreads();
    int vo = t & 15, bo = t >> 4;
    out[(size_t)bo * N + blockIdx.x * 16 + vo] = lds[vo * 17 + bo];  // coalesced
}

extern "C" void kernel_launch(void* const* d_in, const int* in_sizes, int n_in,
                              void* d_out, int out_size, void* d_ws, size_t ws_size,
                              hipStream_t stream) {
    const float* vert  = (const float*)d_in[0];   // (B, N, 3) fp32
    const int*   faces = (const int*)d_in[1];     // (F, 3) int32
    float* out = (float*)d_out;                   // (B, N) fp32
    char* ws = (char*)d_ws;
    (void)ws_size;  // WS_NEED ~44 MB; harness proven >= 63 MB in round 2

    unsigned short* vt      = (unsigned short*)(ws + OFF_VT);
    int*            adj     = (int*)(ws + OFF_ADJ);
    unsigned*       deg     = (unsigned*)(ws + OFF_DEG);
    unsigned*       counter = (unsigned*)(ws + OFF_CNT);
    unsigned*       start   = (unsigned*)(ws + OFF_STA);
    unsigned*       rank    = (unsigned*)(ws + OFF_RNK);

    // zero deg + counter in one contiguous memset (start/rank/adj fully overwritten)
    hipMemsetAsync(ws + OFF_DEG, 0, (OFF_CNT + 256) - OFF_DEG, stream);

    uls_transpose<<<N / 16, 256, 0, stream>>>(vert, vt);
    uls_rank<<<(C3 + 255) / 256, 256, 0, stream>>>(faces, deg, rank);
    uls_alloc<<<(N + 255) / 256, 256, 0, stream>>>(deg, start, counter);
    uls_fill<<<(C3 + 255) / 256, 256, 0, stream>>>(faces, start, rank, adj);
    uls_gather<<<N / 16, 256, 0, stream>>>(vt, adj, start, deg, out);
}

// Round 5
// 264.643 us; speedup vs baseline: 1.3208x; 1.0092x over previous
//
#include <hip/hip_runtime.h>

// Problem constants (fixed by the reference file).
static constexpr int B = 16;
static constexpr int N = 250000;   // 15625 * 16
static constexpr int F = 500000;
static constexpr int C3 = 3 * F;   // corners = 1,500,000
static constexpr int E = 6 * F;    // directed edges = 3,000,000 (even per vertex)
static constexpr int RW = 48;      // ushorts per vt row: 3 comps * 16 batches (96 B)

// ---- workspace layout (bytes) ----
static constexpr size_t OFF_VT  = 0;                                        // ushort[N][48] = 24 MB
static constexpr size_t OFF_ADJ = (size_t)N * RW * 2;                       // int[E] = 12 MB
static constexpr size_t OFF_DEG = OFF_ADJ + (size_t)E * sizeof(int);        // uint[N]
static constexpr size_t OFF_CNT = OFF_DEG + (size_t)N * sizeof(unsigned);   // uint (padded 256)
static constexpr size_t OFF_STA = OFF_CNT + 256;                            // uint[N]
static constexpr size_t OFF_RNK = OFF_STA + (size_t)N * sizeof(unsigned);   // uint[3F] = 6 MB
static constexpr size_t WS_NEED = OFF_RNK + (size_t)C3 * sizeof(unsigned);  // ~44 MB (< proven 63 MB)

__device__ __forceinline__ unsigned short f2bf(float f) {
    unsigned u = __float_as_uint(f);
    return (unsigned short)((u + 0x7FFFu + ((u >> 16) & 1u)) >> 16);  // RNE
}

// Fused: (B,N,3) fp32 -> (N,3,16) bf16 transpose  +  corner ranking.
// Transpose is BW-bound, ranking is atomic-latency-bound -> co-schedule.
__global__ __launch_bounds__(256) void uls_setup(
    const float* __restrict__ vert, const int* __restrict__ faces,
    unsigned short* __restrict__ vt, unsigned* __restrict__ deg,
    unsigned* __restrict__ rank)
{
    __shared__ unsigned short lus[16 * RW];   // 768 ushorts
    int t = threadIdx.x;
    int n0 = blockIdx.x * 16;
    int b = t >> 4, v = t & 15;

    // rank part: issue the long-latency atomic FIRST so it hides behind
    // the transpose's memory work and the barrier.
    int e = blockIdx.x * 256 + t;             // 4M threads cover C3=1.5M corners
    unsigned rv = 0;
    bool e_ok = (e < C3);
    int dst = e_ok ? faces[e] : 0;            // coalesced 4 B
    if (e_ok) rv = atomicAdd(&deg[dst], 2u);  // the only atomic in the pipeline

    const float* s = vert + (size_t)b * (N * 3) + (size_t)(n0 + v) * 3;
    lus[v * RW + 0 * 16 + b] = f2bf(s[0]);
    lus[v * RW + 1 * 16 + b] = f2bf(s[1]);
    lus[v * RW + 2 * 16 + b] = f2bf(s[2]);
    __syncthreads();
    // 768 ushorts = 192 uint2; threads 0..191 write 8 B each (coalesced)
    const uint2* lu2 = (const uint2*)lus;
    uint2* d2 = (uint2*)(vt + (size_t)n0 * RW);
    if (t < 192) d2[t] = lu2[t];

    if (e_ok) rank[e] = rv;                   // coalesced 4 B store
}

// start[n] = block-local exclusive scan + atomically allocated block base.
__global__ __launch_bounds__(256) void uls_alloc(
    const unsigned* __restrict__ deg, unsigned* __restrict__ start,
    unsigned* __restrict__ counter)
{
    __shared__ unsigned s[256];
    __shared__ unsigned base;
    int t = threadIdx.x;
    int n = blockIdx.x * 256 + t;
    unsigned d = (n < N) ? deg[n] : 0u;
    s[t] = d;
    __syncthreads();
    for (int off = 1; off < 256; off <<= 1) {
        unsigned v = (t >= off) ? s[t - off] : 0u;
        __syncthreads();
        s[t] += v;
        __syncthreads();
    }
    if (t == 255) base = atomicAdd(counter, s[255]);
    __syncthreads();
    if (n < N) start[n] = base + (s[t] - d);
}

// Atomic-free placement: slot = start[dst] + rank[e].
__global__ __launch_bounds__(256) void uls_fill(
    const int* __restrict__ faces, const unsigned* __restrict__ start,
    const unsigned* __restrict__ rank, int* __restrict__ adj)
{
    int e = blockIdx.x * 256 + threadIdx.x;
    if (e >= C3) return;
    int f = e / 3;
    int c = e - 3 * f;
    int a  = faces[3 * f + 0];
    int b  = faces[3 * f + 1];
    int cc = faces[3 * f + 2];
    int dst = (c == 0) ? a : (c == 1) ? b : cc;
    int p0  = (c == 0) ? b : a;
    int p1  = (c == 2) ? b : cc;
    unsigned p = start[dst] + rank[e];       // both even -> 8 B aligned
    *(int2*)(adj + p) = make_int2(p0, p1);
}

// 4 lanes per vertex; lane q owns batches 4q..4q+3 via uint2 (8 B) loads.
// One wave instruction covers 16 neighbor rows x 32 B = 512 B (4x fewer
// VMEM instructions than the 16-lane/ushort version; identical traffic).
__device__ __forceinline__ void acc_row(const unsigned short* __restrict__ r,
                                        int q, float (&acc)[3][4]) {
#pragma unroll
    for (int c = 0; c < 3; ++c) {
        uint2 u = *(const uint2*)(r + c * 16 + 4 * q);  // 8 B aligned
        acc[c][0] += __uint_as_float(u.x << 16);
        acc[c][1] += __uint_as_float(u.x & 0xFFFF0000u);
        acc[c][2] += __uint_as_float(u.y << 16);
        acc[c][3] += __uint_as_float(u.y & 0xFFFF0000u);
    }
}

__global__ __launch_bounds__(256) void uls_gather(
    const unsigned short* __restrict__ vt, const int* __restrict__ adj,
    const unsigned* __restrict__ start, const unsigned* __restrict__ deg,
    float* __restrict__ out)
{
    __shared__ float lds[16 * 65];           // [batch][vert], stride 65
    int t = threadIdx.x;
    int q = t & 3;                           // batch quarter
    int v = t >> 2;                          // vertex within block (0..63)
    int n = blockIdx.x * 64 + v;
    bool n_ok = (n < N);

    unsigned d  = n_ok ? deg[n]   : 0u;      // uniform per 4-lane group
    unsigned s0 = n_ok ? start[n] : 0u;

    float acc[3][4] = {{0.f,0.f,0.f,0.f},{0.f,0.f,0.f,0.f},{0.f,0.f,0.f,0.f}};
    unsigned j = 0;
    for (; j + 4 <= d; j += 4) {             // 4 rows x 3 comps = 12 loads in flight
        int2 p0 = *(const int2*)(adj + s0 + j);
        int2 p1 = *(const int2*)(adj + s0 + j + 2);
        acc_row(vt + (size_t)p0.x * RW, q, acc);
        acc_row(vt + (size_t)p0.y * RW, q, acc);
        acc_row(vt + (size_t)p1.x * RW, q, acc);
        acc_row(vt + (size_t)p1.y * RW, q, acc);
    }
    if (j < d) {                             // deg even: remainder exactly 0 or 2
        int2 p0 = *(const int2*)(adj + s0 + j);
        acc_row(vt + (size_t)p0.x * RW, q, acc);
        acc_row(vt + (size_t)p0.y * RW, q, acc);
    }

    if (n_ok) {
        float self[3][4] = {{0.f,0.f,0.f,0.f},{0.f,0.f,0.f,0.f},{0.f,0.f,0.f,0.f}};
        const unsigned short* rs = vt + (size_t)n * RW;
#pragma unroll
        for (int c = 0; c < 3; ++c) {
            uint2 u = *(const uint2*)(rs + c * 16 + 4 * q);
            self[c][0] = __uint_as_float(u.x << 16);
            self[c][1] = __uint_as_float(u.x & 0xFFFF0000u);
            self[c][2] = __uint_as_float(u.y << 16);
            self[c][3] = __uint_as_float(u.y & 0xFFFF0000u);
        }
        float inv = 1.0f / fmaxf((float)d, 1.0f);
#pragma unroll
        for (int k = 0; k < 4; ++k) {
            float lx = acc[0][k] * inv - self[0][k];
            float ly = acc[1][k] * inv - self[1][k];
            float lz = acc[2][k] * inv - self[2][k];
            lds[(4 * q + k) * 65 + v] = sqrtf(lx * lx + ly * ly + lz * lz);
        }
    }
    __syncthreads();
    // coalesced output: thread t writes 4 batches of vertex (blockIdx*64 + (t&63))
    int vo = t & 63;
    int nn = blockIdx.x * 64 + vo;
    if (nn < N) {
#pragma unroll
        for (int k = 0; k < 4; ++k) {
            int bo = (t >> 6) + 4 * k;
            out[(size_t)bo * N + nn] = lds[bo * 65 + vo];
        }
    }
}

extern "C" void kernel_launch(void* const* d_in, const int* in_sizes, int n_in,
                              void* d_out, int out_size, void* d_ws, size_t ws_size,
                              hipStream_t stream) {
    const float* vert  = (const float*)d_in[0];   // (B, N, 3) fp32
    const int*   faces = (const int*)d_in[1];     // (F, 3) int32
    float* out = (float*)d_out;                   // (B, N) fp32
    char* ws = (char*)d_ws;
    (void)ws_size;  // WS_NEED ~44 MB; harness proven >= 63 MB in round 2

    unsigned short* vt      = (unsigned short*)(ws + OFF_VT);
    int*            adj     = (int*)(ws + OFF_ADJ);
    unsigned*       deg     = (unsigned*)(ws + OFF_DEG);
    unsigned*       counter = (unsigned*)(ws + OFF_CNT);
    unsigned*       start   = (unsigned*)(ws + OFF_STA);
    unsigned*       rank    = (unsigned*)(ws + OFF_RNK);

    // zero deg + counter (start/rank/adj fully overwritten downstream)
    hipMemsetAsync(ws + OFF_DEG, 0, (OFF_CNT + 256) - OFF_DEG, stream);

    uls_setup<<<N / 16, 256, 0, stream>>>(vert, faces, vt, deg, rank);
    uls_alloc<<<(N + 255) / 256, 256, 0, stream>>>(deg, start, counter);
    uls_fill<<<(C3 + 255) / 256, 256, 0, stream>>>(faces, start, rank, adj);
    uls_gather<<<(N + 63) / 64, 256, 0, stream>>>(vt, adj, start, deg, out);
}